// Round 1
// baseline (1199.464 us; speedup 1.0000x reference)
//
#include <hip/hip_runtime.h>
#include <cmath>

#define NWALK 4096
#define NXD   48      // N = NF*D
#define HID   256
#define TI    8       // W2 tile rows
#define NTILES (HID / TI)

// GAUSS_CONST = V0 / (sqrt(2*pi)*sigma0), V0=1, sigma0=0.5
#define GCONST 0.7978845608028654f

__global__ __launch_bounds__(256) void eloc_kernel(
    const float* __restrict__ x,
    const float* __restrict__ W1,
    const float* __restrict__ b1,
    const float* __restrict__ W2,
    const float* __restrict__ b2,
    const float* __restrict__ w3,
    float* __restrict__ out)
{
    __shared__ float xs[NXD];
    __shared__ float h1s[HID];
    __shared__ float us[HID];
    __shared__ float rs[HID];
    __shared__ float As[HID * NXD];   // As[i*48 + k] = t1_i * W1[k,i]
    __shared__ float W2t[TI * HID];   // tile of W2 rows
    __shared__ float red[4][4];

    const int w   = blockIdx.x;
    const int tid = threadIdx.x;

    if (tid < NXD) xs[tid] = x[w * NXD + tid];
    __syncthreads();

    // ---- layer 1: hidden unit i = tid ----
    float w1r[NXD];
    float a1 = b1[tid];
    float S  = 0.f;
    #pragma unroll
    for (int k = 0; k < NXD; ++k) {
        float v = W1[k * HID + tid];      // coalesced across tid
        w1r[k] = v;
        a1 = fmaf(xs[k], v, a1);
        S  = fmaf(v, v, S);
    }
    float h1 = tanhf(a1);
    float t1 = 1.f - h1 * h1;
    h1s[tid] = h1;
    {
        float4* Arow = (float4*)&As[tid * NXD];   // 48*4B = 192B, 16B aligned
        #pragma unroll
        for (int kq = 0; kq < NXD / 4; ++kq) {
            Arow[kq] = make_float4(t1 * w1r[4*kq+0], t1 * w1r[4*kq+1],
                                   t1 * w1r[4*kq+2], t1 * w1r[4*kq+3]);
        }
    }
    __syncthreads();

    // ---- layer 2 pre-activation: a2_j, j = tid ----
    float a2 = b2[tid];
    #pragma unroll 16
    for (int i = 0; i < HID; ++i)
        a2 = fmaf(h1s[i], W2[i * HID + tid], a2);   // coalesced across tid
    float h2 = tanhf(a2);
    float t2 = 1.f - h2 * h2;
    float u  = w3[tid] * t2;
    us[tid] = u;

    // ---- M sweep: m[k] = M[k, j=tid], Q = sum_k M^2 ; fused r = W2 u ----
    float4 m[12];
    #pragma unroll
    for (int kq = 0; kq < 12; ++kq) m[kq] = make_float4(0.f, 0.f, 0.f, 0.f);

    const int i_loc = tid >> 5;   // 0..7 row within tile
    const int j0    = tid & 31;

    for (int it = 0; it < NTILES; ++it) {
        __syncthreads();  // protect previous tile use (and us[] on it==0)
        {   // load 8x256 fp32 tile, coalesced float4
            float4*       dst = (float4*)W2t;
            const float4* src = (const float4*)(W2 + it * TI * HID);
            dst[tid]       = src[tid];
            dst[256 + tid] = src[256 + tid];
        }
        __syncthreads();

        #pragma unroll
        for (int r = 0; r < TI; ++r) {
            float wv = W2t[r * HID + tid];                        // conflict-free
            const float4* a4 = (const float4*)&As[(it * TI + r) * NXD];  // broadcast
            #pragma unroll
            for (int kq = 0; kq < 12; ++kq) {
                float4 a = a4[kq];
                m[kq].x = fmaf(a.x, wv, m[kq].x);
                m[kq].y = fmaf(a.y, wv, m[kq].y);
                m[kq].z = fmaf(a.z, wv, m[kq].z);
                m[kq].w = fmaf(a.w, wv, m[kq].w);
            }
        }

        // fused r_i = sum_j W2[i,j] u_j for the 8 rows of this tile
        float rp = 0.f;
        #pragma unroll
        for (int c = 0; c < 8; ++c) {
            int jj = j0 + 32 * c;
            rp = fmaf(W2t[i_loc * HID + jj], us[jj], rp);
        }
        #pragma unroll
        for (int off = 16; off > 0; off >>= 1)
            rp += __shfl_down(rp, off, 32);
        if (j0 == 0) rs[it * TI + i_loc] = rp;
    }
    __syncthreads();

    // ---- scalars ----
    float Q = 0.f;
    #pragma unroll
    for (int kq = 0; kq < 12; ++kq) {
        Q += m[kq].x * m[kq].x + m[kq].y * m[kq].y
           + m[kq].z * m[kq].z + m[kq].w * m[kq].w;
    }
    float term1 = u * h2 * Q;                 // sum_j u_j h2_j Q_j
    float term2 = S * h1 * t1 * rs[tid];      // sum_i S_i h1_i t1_i r_i
    float gg = 0.f, pot = 0.f;
    if (tid < NXD) {
        float g = 0.f;
        #pragma unroll 8
        for (int i = 0; i < HID; ++i)
            g = fmaf(As[i * NXD + tid], rs[i], g);   // g_k = sum_i As[i][k] r_i
        gg  = g * g;
        pot = 0.5f * xs[tid] * xs[tid];
    }

    // ---- block reduction of (term1, term2, gg, pot) ----
    float4 v = make_float4(term1, term2, gg, pot);
    #pragma unroll
    for (int off = 32; off > 0; off >>= 1) {
        v.x += __shfl_down(v.x, off, 64);
        v.y += __shfl_down(v.y, off, 64);
        v.z += __shfl_down(v.z, off, 64);
        v.w += __shfl_down(v.w, off, 64);
    }
    const int wave = tid >> 6;
    if ((tid & 63) == 0) {
        red[wave][0] = v.x; red[wave][1] = v.y;
        red[wave][2] = v.z; red[wave][3] = v.w;
    }
    __syncthreads();

    if (tid == 0) {
        float T1 = red[0][0] + red[1][0] + red[2][0] + red[3][0];
        float T2 = red[0][1] + red[1][1] + red[2][1] + red[3][1];
        float GG = red[0][2] + red[1][2] + red[2][2] + red[3][2];
        float PT = red[0][3] + red[1][3] + red[2][3] + red[3][3];

        float lap = -2.f * (T1 + T2);
        float kin = -0.5f * (lap + GG);

        // interaction: pairs (f,i) with i>f in triu((16,3),k=1): (0,1),(0,2),(1,2)
        float d01 = (xs[0]-xs[1])*(xs[0]-xs[1]) + (xs[2]-xs[1])*(xs[2]-xs[1]);
        float d02 = (xs[0]-xs[2])*(xs[0]-xs[2]) + (xs[1]-xs[2])*(xs[1]-xs[2]);
        float d12 = (xs[3]-xs[5])*(xs[3]-xs[5]) + (xs[4]-xs[5])*(xs[4]-xs[5]);
        float inter = GCONST * (expf(-2.f*d01) + expf(-2.f*d02) + expf(-2.f*d12));

        float eloc = kin + PT + inter;
        out[w]             = eloc;
        out[NWALK + w]     = kin;
        out[2 * NWALK + w] = PT;
        out[3 * NWALK + w] = inter;
    }
}

extern "C" void kernel_launch(void* const* d_in, const int* in_sizes, int n_in,
                              void* d_out, int out_size, void* d_ws, size_t ws_size,
                              hipStream_t stream) {
    const float* x  = (const float*)d_in[0];
    const float* W1 = (const float*)d_in[1];
    const float* b1 = (const float*)d_in[2];
    const float* W2 = (const float*)d_in[3];
    const float* b2 = (const float*)d_in[4];
    const float* w3 = (const float*)d_in[5];
    // d_in[6] = b3: constant offset, vanishes under differentiation; unused.
    float* out = (float*)d_out;

    eloc_kernel<<<NWALK, 256, 0, stream>>>(x, W1, b1, W2, b2, w3, out);
}

// Round 2
// 152.404 us; speedup vs baseline: 7.8703x; 7.8703x over previous
//
#include <hip/hip_runtime.h>
#include <cmath>

#define NWALK 4096
#define NXD   48
#define HID   256
#define GCONST 0.7978845608028654f

typedef _Float16 half8  __attribute__((ext_vector_type(8)));
typedef _Float16 half2v __attribute__((ext_vector_type(2)));
typedef float    float4v __attribute__((ext_vector_type(4)));

// ---- prep: W2c[j][i] = fp16(W2[i][j]) (MFMA A-operand, i-contiguous);
//            W2p[(i>>1)*512 + j*2 + (i&1)] = fp16(W2[i][j]) (pair-packed for a2/p pass)
__global__ void prep_kernel(const float* __restrict__ W2,
                            _Float16* __restrict__ W2c,
                            _Float16* __restrict__ W2p) {
    const int i = blockIdx.x;     // 0..255 (row of W2)
    const int j = threadIdx.x;    // 0..255 (col of W2)
    float v = W2[i * HID + j];
    _Float16 h = (_Float16)v;
    W2c[j * HID + i] = h;
    W2p[(i >> 1) * 512 + j * 2 + (i & 1)] = h;
}

__global__ __launch_bounds__(256, 3) void eloc_kernel(
    const float* __restrict__ x,
    const float* __restrict__ W1,
    const float* __restrict__ b1,
    const float* __restrict__ b2,
    const float* __restrict__ w3,
    const _Float16* __restrict__ W2c,
    const _Float16* __restrict__ W2p,
    float* __restrict__ out)
{
    __shared__ __align__(16) _Float16 AsT[NXD * HID]; // swizzled [k][i], 24 KB
    __shared__ float xs[NXD];
    __shared__ float h1s[HID];
    __shared__ float cs[HID];      // c_i = S_i h1_i t1_i
    __shared__ float us[HID];      // u_j
    __shared__ float uh2s[HID];    // u_j * h2_j
    __shared__ float gw[4][NXD];
    __shared__ float wred[4][2];   // per-wave {T1 partial, T2 partial}
    __shared__ float ggpot[2];

    const int w    = blockIdx.x;
    const int tid  = threadIdx.x;
    const int wave = tid >> 6;
    const int lane = tid & 63;
    const int n16  = lane & 15;
    const int quad = lane >> 4;

    if (tid < NXD) xs[tid] = x[w * NXD + tid];
    __syncthreads();

    // ---- layer 1 (hidden unit i = tid), stage unscaled W1 column into AsT ----
    const int ihi = tid >> 3, ilo = tid & 7;
    float a1 = b1[tid], S = 0.f;
    #pragma unroll
    for (int k = 0; k < NXD; ++k) {
        float v = W1[k * HID + tid];           // coalesced
        a1 = fmaf(xs[k], v, a1);
        S  = fmaf(v, v, S);
        AsT[k * HID + (((ihi ^ (k & 7)) << 3) | ilo)] = (_Float16)v;
    }
    float h1 = tanhf(a1);
    float t1 = 1.f - h1 * h1;
    h1s[tid] = h1;
    cs[tid]  = S * h1 * t1;
    // scale own column by t1 (no cross-thread access yet)
    #pragma unroll
    for (int k = 0; k < NXD; ++k) {
        int off = k * HID + (((ihi ^ (k & 7)) << 3) | ilo);
        AsT[off] = (_Float16)((float)AsT[off] * t1);
    }
    __syncthreads();

    // ---- fused a2 + p pass over fp16 pair-packed W2 (j = tid) ----
    float a2 = b2[tid], p = 0.f;
    const _Float16* w2col = W2p + tid * 2;
    #pragma unroll 16
    for (int ip = 0; ip < HID / 2; ++ip) {
        half2v hv = *(const half2v*)(w2col + ip * 512);
        float v0 = (float)hv[0], v1 = (float)hv[1];
        a2 = fmaf(h1s[2 * ip],     v0, a2);
        a2 = fmaf(h1s[2 * ip + 1], v1, a2);
        p  = fmaf(cs[2 * ip],      v0, p);
        p  = fmaf(cs[2 * ip + 1],  v1, p);
    }
    float h2 = tanhf(a2);
    float t2 = 1.f - h2 * h2;
    float u  = w3[tid] * t2;
    us[tid]   = u;
    uh2s[tid] = u * h2;
    float t2p = u * p;              // term2 per-thread partial
    __syncthreads();

    // ---- MFMA: Mt[j,k] = sum_i W2c[j][i] * AsT[k][i] ----
    // wave owns j-tiles {4w..4w+3}; 3 k-tiles (k<48); K=256 in 8 steps of 32
    float4v acc[4][3];
    #pragma unroll
    for (int a = 0; a < 4; ++a)
        #pragma unroll
        for (int kt = 0; kt < 3; ++kt)
            acc[a][kt] = (float4v){0.f, 0.f, 0.f, 0.f};

    #pragma unroll
    for (int step = 0; step < 8; ++step) {
        const int i0 = step * 32 + quad * 8;
        half8 af[4];
        #pragma unroll
        for (int a = 0; a < 4; ++a) {
            int j = (wave * 4 + a) * 16 + n16;     // A[m=lane&15][kk=quad*8+t]
            af[a] = *(const half8*)(W2c + j * HID + i0);
        }
        half8 bf[3];
        #pragma unroll
        for (int kt = 0; kt < 3; ++kt) {
            int k = kt * 16 + n16;                 // B[kk=quad*8+t][n=lane&15]
            int goff = k * HID + ((((step * 4 + quad) ^ (k & 7)) << 3));
            bf[kt] = *(const half8*)(AsT + goff);
        }
        #pragma unroll
        for (int a = 0; a < 4; ++a)
            #pragma unroll
            for (int kt = 0; kt < 3; ++kt)
                acc[a][kt] = __builtin_amdgcn_mfma_f32_16x16x32_f16(
                    af[a], bf[kt], acc[a][kt], 0, 0, 0);
    }

    // ---- epilogue: T1 = sum_j u h2 Q_j ; g_k = sum_j Mt[j,k] u_j ----
    float t1p = 0.f;
    float gp[3] = {0.f, 0.f, 0.f};
    #pragma unroll
    for (int a = 0; a < 4; ++a) {
        #pragma unroll
        for (int reg = 0; reg < 4; ++reg) {
            int j = (wave * 4 + a) * 16 + quad * 4 + reg;   // C/D: row=quad*4+reg
            float uh2 = uh2s[j];
            float uu  = us[j];
            #pragma unroll
            for (int kt = 0; kt < 3; ++kt) {
                float m = acc[a][kt][reg];
                t1p    = fmaf(m * m, uh2, t1p);
                gp[kt] = fmaf(m, uu, gp[kt]);
            }
        }
    }
    // wave-reduce T1, T2 partials
    float rt1 = t1p, rt2 = t2p;
    #pragma unroll
    for (int off = 32; off > 0; off >>= 1) {
        rt1 += __shfl_down(rt1, off, 64);
        rt2 += __shfl_down(rt2, off, 64);
    }
    // quad-reduce g partials (lanes sharing n hold same k)
    #pragma unroll
    for (int kt = 0; kt < 3; ++kt) {
        gp[kt] += __shfl_xor(gp[kt], 16, 64);
        gp[kt] += __shfl_xor(gp[kt], 32, 64);
    }
    if (lane == 0) { wred[wave][0] = rt1; wred[wave][1] = rt2; }
    if (lane < 16) {
        #pragma unroll
        for (int kt = 0; kt < 3; ++kt) gw[wave][kt * 16 + lane] = gp[kt];
    }
    __syncthreads();

    float ggp = 0.f, potp = 0.f;
    if (tid < NXD) {
        float g = gw[0][tid] + gw[1][tid] + gw[2][tid] + gw[3][tid];
        ggp  = g * g;
        potp = 0.5f * xs[tid] * xs[tid];
    }
    if (wave == 0) {
        #pragma unroll
        for (int off = 32; off > 0; off >>= 1) {
            ggp  += __shfl_down(ggp, off, 64);
            potp += __shfl_down(potp, off, 64);
        }
        if (lane == 0) { ggpot[0] = ggp; ggpot[1] = potp; }
    }
    __syncthreads();

    if (tid == 0) {
        float T1 = wred[0][0] + wred[1][0] + wred[2][0] + wred[3][0];
        float T2 = wred[0][1] + wred[1][1] + wred[2][1] + wred[3][1];
        float GG = ggpot[0], PT = ggpot[1];
        float kin = T1 + T2 - 0.5f * GG;   // = -0.5*(lap + GG), lap = -2(T1+T2)

        float d01 = (xs[0]-xs[1])*(xs[0]-xs[1]) + (xs[2]-xs[1])*(xs[2]-xs[1]);
        float d02 = (xs[0]-xs[2])*(xs[0]-xs[2]) + (xs[1]-xs[2])*(xs[1]-xs[2]);
        float d12 = (xs[3]-xs[5])*(xs[3]-xs[5]) + (xs[4]-xs[5])*(xs[4]-xs[5]);
        float inter = GCONST * (expf(-2.f*d01) + expf(-2.f*d02) + expf(-2.f*d12));

        out[w]             = kin + PT + inter;
        out[NWALK + w]     = kin;
        out[2 * NWALK + w] = PT;
        out[3 * NWALK + w] = inter;
    }
}

extern "C" void kernel_launch(void* const* d_in, const int* in_sizes, int n_in,
                              void* d_out, int out_size, void* d_ws, size_t ws_size,
                              hipStream_t stream) {
    const float* x  = (const float*)d_in[0];
    const float* W1 = (const float*)d_in[1];
    const float* b1 = (const float*)d_in[2];
    const float* W2 = (const float*)d_in[3];
    const float* b2 = (const float*)d_in[4];
    const float* w3 = (const float*)d_in[5];
    float* out = (float*)d_out;

    _Float16* W2c = (_Float16*)d_ws;                    // 128 KB
    _Float16* W2p = (_Float16*)d_ws + HID * HID;        // 128 KB

    prep_kernel<<<HID, HID, 0, stream>>>(W2, W2c, W2p);
    eloc_kernel<<<NWALK, 256, 0, stream>>>(x, W1, b1, b2, w3, W2c, W2p, out);
}

// Round 3
// 143.089 us; speedup vs baseline: 8.3827x; 1.0651x over previous
//
#include <hip/hip_runtime.h>
#include <cmath>

#define NWALK 4096
#define NXD   48
#define HID   256
#define GCONST 0.7978845608028654f

typedef _Float16 half8   __attribute__((ext_vector_type(8)));
typedef _Float16 half2v  __attribute__((ext_vector_type(2)));
typedef float    float4v __attribute__((ext_vector_type(4)));

// ---- prep: W2c[j*256+i] = fp16(W2[i*256+j]), tiled transpose, coalesced both ways
__global__ __launch_bounds__(256) void prep_kernel(const float* __restrict__ W2,
                                                   _Float16* __restrict__ W2c) {
    __shared__ float tile[64][65];
    const int bi = blockIdx.x;          // i-tile
    const int bj = blockIdx.y;          // j-tile
    const int tx = threadIdx.x & 63;
    const int ty = threadIdx.x >> 6;    // 0..3
    #pragma unroll
    for (int r = 0; r < 16; ++r) {
        int il = ty * 16 + r;
        tile[tx][il] = W2[(bi * 64 + il) * HID + bj * 64 + tx];  // [j_local][i_local]
    }
    __syncthreads();
    #pragma unroll
    for (int r = 0; r < 16; ++r) {
        int jl = ty * 16 + r;
        W2c[(bj * 64 + jl) * HID + bi * 64 + tx] = (_Float16)tile[jl][tx];
    }
}

__global__ __launch_bounds__(256, 4) void eloc_kernel(
    const float* __restrict__ x,
    const float* __restrict__ W1,
    const float* __restrict__ b1,
    const float* __restrict__ b2,
    const float* __restrict__ w3,
    const _Float16* __restrict__ W2c,
    float* __restrict__ out)
{
    // AsT rows 0..47: t1_i*W1[k,i] (XOR-swizzled); row 48: h1_i; row 49: c_i
    __shared__ __align__(16) _Float16 AsT[50 * HID];   // 25.6 KB
    __shared__ float xs[NXD];
    __shared__ float b2s[HID], w3s[HID];
    __shared__ float us[HID], uh2s[HID], ps[HID];
    __shared__ float gw[4][NXD];
    __shared__ float wred[4][2];
    __shared__ float ggpot[2];

    const int w    = blockIdx.x;
    const int tid  = threadIdx.x;
    const int wave = tid >> 6;
    const int lane = tid & 63;
    const int n16  = lane & 15;
    const int quad = lane >> 4;

    if (tid < NXD) xs[tid] = x[w * NXD + tid];
    b2s[tid] = b2[tid];
    w3s[tid] = w3[tid];
    __syncthreads();

    // ---- layer 1 (hidden unit i = tid): a1, S, fp16 W1 column in registers ----
    const int ihi = tid >> 3, ilo = tid & 7;
    float a1 = b1[tid], S = 0.f;
    half2v vh[24];
    #pragma unroll
    for (int kp = 0; kp < 24; ++kp) {
        float v0 = W1[(2 * kp)     * HID + tid];   // coalesced
        float v1 = W1[(2 * kp + 1) * HID + tid];
        a1 = fmaf(xs[2 * kp],     v0, a1);
        a1 = fmaf(xs[2 * kp + 1], v1, a1);
        S  = fmaf(v0, v0, S);
        S  = fmaf(v1, v1, S);
        vh[kp][0] = (_Float16)v0;
        vh[kp][1] = (_Float16)v1;
    }
    float h1 = tanhf(a1);
    float t1 = 1.f - h1 * h1;
    {
        _Float16 t1h = (_Float16)t1;
        half2v t1v = {t1h, t1h};
        #pragma unroll
        for (int kp = 0; kp < 24; ++kp) {
            half2v s = vh[kp] * t1v;               // v_pk_mul_f16
            int k0 = 2 * kp, k1 = 2 * kp + 1;
            AsT[k0 * HID + (((ihi ^ (k0 & 7)) << 3) | ilo)] = s[0];
            AsT[k1 * HID + (((ihi ^ (k1 & 7)) << 3) | ilo)] = s[1];
        }
    }
    AsT[48 * HID + tid]                        = (_Float16)h1;              // 48&7=0
    AsT[49 * HID + (((ihi ^ 1) << 3) | ilo)]   = (_Float16)(S * h1 * t1);   // 49&7=1
    __syncthreads();

    // ---- MFMA: Mt[j,k] = sum_i W2[i,j]*As[i,k]; kt=3 gives a2 (col0), p (col1) ----
    float4v acc[4][4];
    #pragma unroll
    for (int a = 0; a < 4; ++a)
        #pragma unroll
        for (int kt = 0; kt < 4; ++kt)
            acc[a][kt] = (float4v){0.f, 0.f, 0.f, 0.f};

    #pragma unroll
    for (int step = 0; step < 8; ++step) {
        const int i0 = step * 32 + quad * 8;
        half8 af[4];
        #pragma unroll
        for (int a = 0; a < 4; ++a) {
            int j = (wave * 4 + a) * 16 + n16;          // A[m=n16][kk=quad*8+t]
            af[a] = *(const half8*)(W2c + j * HID + i0);
        }
        half8 bf[4];
        #pragma unroll
        for (int kt = 0; kt < 4; ++kt) {
            int krow = (kt < 3) ? (kt * 16 + n16) : (48 + (n16 & 1));
            int goff = krow * HID + ((((step * 4 + quad) ^ (krow & 7)) << 3));
            bf[kt] = *(const half8*)(AsT + goff);       // B[kk][n=n16]
        }
        #pragma unroll
        for (int a = 0; a < 4; ++a)
            #pragma unroll
            for (int kt = 0; kt < 4; ++kt)
                acc[a][kt] = __builtin_amdgcn_mfma_f32_16x16x32_f16(
                    af[a], bf[kt], acc[a][kt], 0, 0, 0);
    }

    // ---- activations from kt=3 accumulator columns 0 (a2) and 1 (p) ----
    if (n16 == 0) {
        #pragma unroll
        for (int a = 0; a < 4; ++a)
            #pragma unroll
            for (int reg = 0; reg < 4; ++reg) {
                int j = (wave * 4 + a) * 16 + quad * 4 + reg;
                float a2 = acc[a][3][reg] + b2s[j];
                float h2 = tanhf(a2);
                float t2 = 1.f - h2 * h2;
                float u  = w3s[j] * t2;
                us[j]   = u;
                uh2s[j] = u * h2;
            }
    } else if (n16 == 1) {
        #pragma unroll
        for (int a = 0; a < 4; ++a)
            #pragma unroll
            for (int reg = 0; reg < 4; ++reg) {
                int j = (wave * 4 + a) * 16 + quad * 4 + reg;
                ps[j] = acc[a][3][reg];
            }
    }
    __syncthreads();

    // ---- T1 = sum_j u h2 Q_j ; g_k = sum_j Mt[j,k] u_j ; T2 = sum_j u_j p_j ----
    float t1p = 0.f;
    float gp[3] = {0.f, 0.f, 0.f};
    #pragma unroll
    for (int a = 0; a < 4; ++a) {
        #pragma unroll
        for (int reg = 0; reg < 4; ++reg) {
            int j = (wave * 4 + a) * 16 + quad * 4 + reg;
            float uh2 = uh2s[j];
            float uu  = us[j];
            #pragma unroll
            for (int kt = 0; kt < 3; ++kt) {
                float m = acc[a][kt][reg];
                t1p    = fmaf(m * m, uh2, t1p);
                gp[kt] = fmaf(m, uu, gp[kt]);
            }
        }
    }
    float rt1 = t1p;
    float rt2 = us[tid] * ps[tid];   // T2 per-thread partial
    #pragma unroll
    for (int off = 32; off > 0; off >>= 1) {
        rt1 += __shfl_down(rt1, off, 64);
        rt2 += __shfl_down(rt2, off, 64);
    }
    #pragma unroll
    for (int kt = 0; kt < 3; ++kt) {
        gp[kt] += __shfl_xor(gp[kt], 16, 64);
        gp[kt] += __shfl_xor(gp[kt], 32, 64);
    }
    if (lane == 0) { wred[wave][0] = rt1; wred[wave][1] = rt2; }
    if (lane < 16) {
        #pragma unroll
        for (int kt = 0; kt < 3; ++kt) gw[wave][kt * 16 + lane] = gp[kt];
    }
    __syncthreads();

    float ggp = 0.f, potp = 0.f;
    if (tid < NXD) {
        float g = gw[0][tid] + gw[1][tid] + gw[2][tid] + gw[3][tid];
        ggp  = g * g;
        potp = 0.5f * xs[tid] * xs[tid];
    }
    if (wave == 0) {
        #pragma unroll
        for (int off = 32; off > 0; off >>= 1) {
            ggp  += __shfl_down(ggp, off, 64);
            potp += __shfl_down(potp, off, 64);
        }
        if (lane == 0) { ggpot[0] = ggp; ggpot[1] = potp; }
    }
    __syncthreads();

    if (tid == 0) {
        float T1 = wred[0][0] + wred[1][0] + wred[2][0] + wred[3][0];
        float T2 = wred[0][1] + wred[1][1] + wred[2][1] + wred[3][1];
        float GG = ggpot[0], PT = ggpot[1];
        float kin = T1 + T2 - 0.5f * GG;

        float d01 = (xs[0]-xs[1])*(xs[0]-xs[1]) + (xs[2]-xs[1])*(xs[2]-xs[1]);
        float d02 = (xs[0]-xs[2])*(xs[0]-xs[2]) + (xs[1]-xs[2])*(xs[1]-xs[2]);
        float d12 = (xs[3]-xs[5])*(xs[3]-xs[5]) + (xs[4]-xs[5])*(xs[4]-xs[5]);
        float inter = GCONST * (expf(-2.f*d01) + expf(-2.f*d02) + expf(-2.f*d12));

        out[w]             = kin + PT + inter;
        out[NWALK + w]     = kin;
        out[2 * NWALK + w] = PT;
        out[3 * NWALK + w] = inter;
    }
}

extern "C" void kernel_launch(void* const* d_in, const int* in_sizes, int n_in,
                              void* d_out, int out_size, void* d_ws, size_t ws_size,
                              hipStream_t stream) {
    const float* x  = (const float*)d_in[0];
    const float* W1 = (const float*)d_in[1];
    const float* b1 = (const float*)d_in[2];
    const float* W2 = (const float*)d_in[3];
    const float* b2 = (const float*)d_in[4];
    const float* w3 = (const float*)d_in[5];
    float* out = (float*)d_out;

    _Float16* W2c = (_Float16*)d_ws;   // 128 KB

    prep_kernel<<<dim3(4, 4), 256, 0, stream>>>(W2, W2c);
    eloc_kernel<<<NWALK, 256, 0, stream>>>(x, W1, b1, b2, w3, W2c, out);
}